// Round 9
// baseline (2698.063 us; speedup 1.0000x reference)
//
#include <hip/hip_runtime.h>
#include <math.h>

#define NN   50000
#define NE   800000
#define ESL  (NE + NN)     // CSR slots incl. one self-loop per node
#define DIN1 128
#define DE   16
#define C    64
#define HID  256
#define DCLS 144
#define KP   160      // DCLS padded to multiple of 32
#define NEGS 0.2f
#define NPB  8
#define NBLK ((NN + 255) / 256)   // 196 scan blocks

// ---- k_cls_mfma geometry (v7: 2 tiles/block, shared A) ----
#define TCH  1024                  // chunk stride: 64 rows * 16B
#define TBUF (18 * TCH)            // 18 chunks = 18432 B per tile
#define LDS_CLS (2 * TBUF + 4096)  // 2 tiles + so[4][4][64] = 40960 B (4 blk/CU exact)

typedef __attribute__((ext_vector_type(8))) short  short8;   // 8 bf16 in 4 VGPRs
typedef __attribute__((ext_vector_type(4))) float  f32x4;

// float -> bf16 (RNE)
__device__ __forceinline__ ushort f2bf(float f) {
    unsigned u = __float_as_uint(f);
    u += 0x7fffu + ((u >> 16) & 1u);
    return (ushort)(u >> 16);
}
__device__ __forceinline__ float bf2f(ushort u) {
    return __uint_as_float(((unsigned)u) << 16);
}
// packed bf16 pair -> two floats (1 op each)
__device__ __forceinline__ float bflo(unsigned w) { return __uint_as_float(w << 16); }
__device__ __forceinline__ float bfhi(unsigned w) { return __uint_as_float(w & 0xffff0000u); }

// ---- degree histogram ----
__global__ void k_deg(const int* __restrict__ dst, int* __restrict__ deg) {
    int e = blockIdx.x * blockDim.x + threadIdx.x;
    if (e < NE) atomicAdd(&deg[dst[e]], 1);
}

// ---- CSR build: scan of (deg+1) -> rowptr (self-loop slot per node) ----
__global__ void k_scan1(const int* __restrict__ deg, int* __restrict__ rowptr,
                        int* __restrict__ bsum) {
    __shared__ int s[256];
    int t = threadIdx.x;
    int i = blockIdx.x * 256 + t;
    int v = (i < NN) ? (deg[i] + 1) : 0;
    s[t] = v;
    __syncthreads();
    for (int off = 1; off < 256; off <<= 1) {
        int u = (t >= off) ? s[t - off] : 0;
        __syncthreads();
        s[t] += u;
        __syncthreads();
    }
    if (i < NN) rowptr[i] = s[t] - v;          // exclusive
    if (t == 255) bsum[blockIdx.x] = s[255];
}

__global__ void k_scan2(int* __restrict__ bsum, int* __restrict__ boff) {
    __shared__ int s[256];
    int t = threadIdx.x;
    int v = (t < NBLK) ? bsum[t] : 0;
    s[t] = v;
    __syncthreads();
    for (int off = 1; off < 256; off <<= 1) {
        int u = (t >= off) ? s[t - off] : 0;
        __syncthreads();
        s[t] += u;
        __syncthreads();
    }
    if (t < NBLK) boff[t] = s[t] - v;          // exclusive
}

__global__ void k_scan3(int* __restrict__ rowptr, const int* __restrict__ boff) {
    int i = blockIdx.x * 256 + threadIdx.x;
    if (i < NN) rowptr[i] += boff[blockIdx.x];
    if (i == 0) rowptr[NN] = ESL;
}

// ---- scatter: permute src + edge_attr(bf16) into CSR order ----
__global__ void k_scatter(const int* __restrict__ src, const int* __restrict__ dst,
                          const float* __restrict__ eattr,
                          const int* __restrict__ rowptr, int* __restrict__ cursor,
                          int* __restrict__ src_perm, ushort* __restrict__ eap) {
    int e = blockIdx.x * blockDim.x + threadIdx.x;
    if (e >= NE) return;
    int d = dst[e];
    int pos = atomicAdd(&cursor[d], 1);
    int idx = rowptr[d] + pos;
    src_perm[idx] = src[e];
    const float4* p4 = (const float4*)&eattr[(size_t)e * DE];
    float4 c0 = p4[0], c1 = p4[1], c2 = p4[2], c3 = p4[3];
    short8 r0, r1;
    r0[0]=f2bf(c0.x); r0[1]=f2bf(c0.y); r0[2]=f2bf(c0.z); r0[3]=f2bf(c0.w);
    r0[4]=f2bf(c1.x); r0[5]=f2bf(c1.y); r0[6]=f2bf(c1.z); r0[7]=f2bf(c1.w);
    r1[0]=f2bf(c2.x); r1[1]=f2bf(c2.y); r1[2]=f2bf(c2.z); r1[3]=f2bf(c2.w);
    r1[4]=f2bf(c3.x); r1[5]=f2bf(c3.y); r1[6]=f2bf(c3.z); r1[7]=f2bf(c3.w);
    short8* q = (short8*)&eap[(size_t)idx * DE];
    q[0] = r0; q[1] = r1;
}

// ---- self-loop mean attr -> written into the CSR self slot ----
__global__ void k_loop_csr(const int* __restrict__ rowptr,
                           ushort* __restrict__ eap, int* __restrict__ src_perm) {
    int wave = threadIdx.x >> 6, lane = threadIdx.x & 63;
    int d = blockIdx.x * 4 + wave;
    if (d >= NN) return;
    int j = lane & 15, g = lane >> 4;
    int kb = rowptr[d], ke1 = rowptr[d + 1] - 1;   // real edges in [kb, ke1)
    float sum = 0.f;
    for (int k = kb + g; k < ke1; k += 4)
        sum += bf2f(eap[(size_t)k * DE + j]);
    sum += __shfl_xor(sum, 16);
    sum += __shfl_xor(sum, 32);
    if (lane < 16)
        eap[(size_t)ke1 * DE + lane] = f2bf(sum / fmaxf((float)(ke1 - kb), 1.0f));
    if (lane == 16) src_perm[ke1] = d;
}

// ---- weight transposes for k_lin: WT[c][K] = W[k][c] ----
// out layout: wlT1[64*128] | wrT1[64*128] | wlT2[64*64] | wrT2[64*64]
__global__ void k_trans(const float* __restrict__ Wl1, const float* __restrict__ Wr1,
                        const float* __restrict__ Wl2, const float* __restrict__ Wr2,
                        float* __restrict__ out) {
    int b = blockIdx.x, c = b & 63, m = b >> 6;
    const float* W = (m == 0) ? Wl1 : (m == 1) ? Wr1 : (m == 2) ? Wl2 : Wr2;
    int K = (m < 2) ? DIN1 : C;
    float* WT = out + ((m < 2) ? m * (64 * DIN1) : 2 * (64 * DIN1) + (m - 2) * (64 * C));
    for (int k = threadIdx.x; k < K; k += 128)
        WT[c * K + k] = W[k * 64 + c];
}

// ---- node linear transforms v2: xl(bf16)=x@Wl+bl, xr(fp32)=x@Wr+br ----
template<int DINT>
__global__ __launch_bounds__(128, 4) void k_lin(
        const float* __restrict__ x,
        const float* __restrict__ WlT, const float* __restrict__ bl,
        const float* __restrict__ WrT, const float* __restrict__ br,
        ushort* __restrict__ xlb, float* __restrict__ xr) {
    __shared__ float sx[NPB * DINT];
    int i0 = blockIdx.x * NPB;
    int t = threadIdx.x;
    {
        const float4* g4 = (const float4*)(x + (size_t)i0 * DINT);
        float4* s4 = (float4*)sx;
#pragma unroll
        for (int f = t; f < NPB * DINT / 4; f += 128) s4[f] = g4[f];
    }
    __syncthreads();
    int c = t & 63, half = t >> 6;
    const float4* wt4 = (const float4*)((half ? WrT : WlT) + (size_t)c * DINT);
    float bb = (half ? br : bl)[c];
    float acc[NPB];
#pragma unroll
    for (int n = 0; n < NPB; ++n) acc[n] = bb;
    const float4* sx4 = (const float4*)sx;
#pragma unroll 4
    for (int k4 = 0; k4 < DINT / 4; ++k4) {
        float4 w = wt4[k4];
#pragma unroll
        for (int n = 0; n < NPB; ++n) {
            float4 xv = sx4[n * (DINT / 4) + k4];
            acc[n] = fmaf(xv.x, w.x, acc[n]);
            acc[n] = fmaf(xv.y, w.y, acc[n]);
            acc[n] = fmaf(xv.z, w.z, acc[n]);
            acc[n] = fmaf(xv.w, w.w, acc[n]);
        }
    }
    if (half == 0) {
#pragma unroll
        for (int n = 0; n < NPB; ++n)
            xlb[(size_t)(i0 + n) * C + c] = f2bf(acc[n]);
    } else {
#pragma unroll
        for (int n = 0; n < NPB; ++n)
            xr[(size_t)(i0 + n) * C + c] = acc[n];
    }
}

// ---- fused GAT layer v2: 4 nodes/block (wave=node), We in LDS, prefetch ----
// Occupancy: 64-thr blocks capped at 16 wg/CU = 16 waves (50%); 256-thr
// blocks + launch_bounds(256,6) -> 24 waves/CU. We/att/bias staged once in
// LDS (shared by 4 waves; 16-lane x 16B reads = 2-way bank alias, free),
// freeing the 64-VGPR wreg array. The serial per-iteration gather chain
// src_perm[k] -> xlb[s] is software-pipelined one iteration ahead so the
// gather latency overlaps the ~90-instruction compute phase.
// Math and summation order identical to v1.
template<int DO_ELU, int OUT_BF16>
__global__ __launch_bounds__(256, 6) void k_gat(
        const int* __restrict__ src_perm, const int* __restrict__ rowptr,
        const ushort* __restrict__ eap,
        const ushort* __restrict__ xlb, const float* __restrict__ xr,
        const float* __restrict__ We, const float* __restrict__ att,
        const float* __restrict__ bias, void* __restrict__ o_) {
    __shared__ float sWe[DE * C];     // [j][c], 4 KB
    __shared__ float sAx[2 * C];      // att | bias
    int tid = threadIdx.x;
    ((float4*)sWe)[tid] = ((const float4*)We)[tid];          // 256*16B = 4KB
    if (tid < 16)      ((float4*)sAx)[tid] = ((const float4*)att)[tid];
    else if (tid < 32) ((float4*)sAx)[tid] = ((const float4*)bias)[tid - 16];
    __syncthreads();

    int wave = tid >> 6, lane = tid & 63;
    int d = blockIdx.x * 4 + wave;    // NN % 4 == 0
    int g = lane >> 4, l = lane & 15;
    int c0 = l * 4;
    float4 xr4 = *(const float4*)&xr[(size_t)d * C + c0];
    float xrv[4] = {xr4.x, xr4.y, xr4.z, xr4.w};

    int kb = rowptr[d], ke = rowptr[d + 1];
    // iteration-0 loads (every node has >=1 slot: the self-loop)
    int ck = kb + g;
    bool valid = ck < ke;
    int kidx = valid ? ck : (ke - 1);
    int s = src_perm[kidx];
    uint2 xlr = *(const uint2*)&xlb[(size_t)s * C + c0];
    const uint4* ep0 = (const uint4*)&eap[(size_t)kidx * DE];
    uint4 e0 = ep0[0], e1 = ep0[1];

    float l_run = 0.f, n_run[4] = {0.f, 0.f, 0.f, 0.f};
    for (int k = kb; k < ke; k += 4) {
        // ---- prefetch iteration k+4 (overlaps compute below) ----
        bool anyn = (k + 4) < ke;            // wave-uniform
        int nk = k + 4 + g;
        bool validn = nk < ke;
        int kidxn = validn ? nk : (ke - 1);
        int sn = s; uint2 xlrn = xlr; uint4 e0n = e0, e1n = e1;
        if (anyn) {
            sn = src_perm[kidxn];
            xlrn = *(const uint2*)&xlb[(size_t)sn * C + c0];
            const uint4* epn = (const uint4*)&eap[(size_t)kidxn * DE];
            e0n = epn[0]; e1n = epn[1];
        }
        // ---- compute current ----
        float xlv[4] = {bflo(xlr.x), bfhi(xlr.x), bflo(xlr.y), bfhi(xlr.y)};
        float m[4];
#pragma unroll
        for (int i = 0; i < 4; ++i) m[i] = xlv[i] + xrv[i];
        unsigned ew[8] = {e0.x, e0.y, e0.z, e0.w, e1.x, e1.y, e1.z, e1.w};
#pragma unroll
        for (int wji = 0; wji < 8; ++wji) {
            float elo = bflo(ew[wji]), ehi = bfhi(ew[wji]);
            float4 w0 = *(const float4*)&sWe[(2 * wji) * C + c0];
            float4 w1 = *(const float4*)&sWe[(2 * wji + 1) * C + c0];
            m[0] = fmaf(elo, w0.x, m[0]);
            m[1] = fmaf(elo, w0.y, m[1]);
            m[2] = fmaf(elo, w0.z, m[2]);
            m[3] = fmaf(elo, w0.w, m[3]);
            m[0] = fmaf(ehi, w1.x, m[0]);
            m[1] = fmaf(ehi, w1.y, m[1]);
            m[2] = fmaf(ehi, w1.z, m[2]);
            m[3] = fmaf(ehi, w1.w, m[3]);
        }
        float4 av = *(const float4*)&sAx[c0];
        float avv[4] = {av.x, av.y, av.z, av.w};
        float p = 0.f;
#pragma unroll
        for (int i = 0; i < 4; ++i) {
            float t = fmaxf(m[i], NEGS * m[i]);   // leaky via max
            p = fmaf(t, avv[i], p);
        }
        p += __shfl_xor(p, 1);
        p += __shfl_xor(p, 2);
        p += __shfl_xor(p, 4);
        p += __shfl_xor(p, 8);
        float pe = valid ? __expf(p) : 0.f;
        l_run += pe;
#pragma unroll
        for (int i = 0; i < 4; ++i) n_run[i] = fmaf(pe, xlv[i], n_run[i]);
        // ---- rotate pipeline ----
        valid = validn; s = sn; xlr = xlrn; e0 = e0n; e1 = e1n;
    }
    l_run += __shfl_xor(l_run, 16);
    l_run += __shfl_xor(l_run, 32);
#pragma unroll
    for (int i = 0; i < 4; ++i) {
        n_run[i] += __shfl_xor(n_run[i], 16);
        n_run[i] += __shfl_xor(n_run[i], 32);
    }
    if (g == 0) {
        float4 bv = *(const float4*)&sAx[64 + c0];
        float bvv[4] = {bv.x, bv.y, bv.z, bv.w};
        float res[4];
#pragma unroll
        for (int i = 0; i < 4; ++i) {
            float v = n_run[i] / l_run + bvv[i];
            if (DO_ELU) v = (v > 0.f) ? v : (__expf(v) - 1.0f);
            res[i] = v;
        }
        if (OUT_BF16) {
            uint2 pk;
            pk.x = (unsigned)f2bf(res[0]) | ((unsigned)f2bf(res[1]) << 16);
            pk.y = (unsigned)f2bf(res[2]) | ((unsigned)f2bf(res[3]) << 16);
            *(uint2*)&((ushort*)o_)[(size_t)d * C + c0] = pk;
        } else {
            float4 pk = {res[0], res[1], res[2], res[3]};
            *(float4*)&((float*)o_)[(size_t)d * C + c0] = pk;
        }
    }
}

// Cw1 [144][256] fp32 -> Cw1T bf16 [256][160] (transpose + zero-pad K)
__global__ void k_cvt_w(const float* __restrict__ Cw1, short* __restrict__ Cw1T) {
    int n = blockIdx.x;
    int k = threadIdx.x;
    Cw1T[n * KP + k] = (k < DCLS) ? (short)f2bf(Cw1[k * HID + n]) : (short)0;
}

// ==== MFMA edge classifier v7: 2 tiles/block, shared A-fragments ====
// (unchanged from round 8 — control kernel, 98 µs measured)
__global__ __launch_bounds__(256, 4) void k_cls_mfma(
        const int* __restrict__ src, const int* __restrict__ dst,
        const float* __restrict__ eattr, const short* __restrict__ h2b,
        const short* __restrict__ Cw1T, const float* __restrict__ Cb1,
        const float* __restrict__ Cw2, const float* __restrict__ Cb2,
        float* __restrict__ out) {
    __shared__ __align__(16) char lds[LDS_CLS];
    int tid = threadIdx.x;
    int ebase = blockIdx.x * 128;
    int lane = tid & 63, wave = tid >> 6;
    int l15 = lane & 15, quad = lane >> 4;
    const char* ApB = (const char*)Cw1T;

    // ---- stage BOTH tiles: per thread 2x (64B row-half + eattr quarter) ----
    {
        int r = tid & 127, h = tid >> 7;        // row r (src<64|dst-64), half h
        int el = r & 63;
        int cb = ((r >> 6) << 3) + (h << 2);    // chunk base: src 0/dst 8, +h*4
        int eg = tid >> 2, q = tid & 3;
#pragma unroll
        for (int t = 0; t < 2; ++t) {
            int eb = ebase + t * 64;
            int node = (r < 64) ? src[eb + el] : dst[eb + el];
            const uint4* g = (const uint4*)(h2b + (size_t)node * C + h * 32);
            uint4 f0 = g[0], f1 = g[1], f2 = g[2], f3 = g[3];
            char* p = lds + t * TBUF + cb * TCH + el * 16;
            *(uint4*)(p) = f0;
            *(uint4*)(p + TCH) = f1;
            *(uint4*)(p + 2 * TCH) = f2;
            *(uint4*)(p + 3 * TCH) = f3;
            float4 ea = *(const float4*)&eattr[(size_t)(eb + eg) * DE + q * 4];
            uint2 pk;
            pk.x = (unsigned)f2bf(ea.x) | ((unsigned)f2bf(ea.y) << 16);
            pk.y = (unsigned)f2bf(ea.z) | ((unsigned)f2bf(ea.w) << 16);
            *(uint2*)(lds + t * TBUF + (16 + (q >> 1)) * TCH + eg * 16 + (q & 1) * 8) = pk;
        }
    }

    // ---- pass-0 A-fragment hoist (global; independent of LDS -> pre-barrier)
    short8 areg[5][2];
#pragma unroll
    for (int kk = 0; kk < 5; ++kk)
#pragma unroll
        for (int mt = 0; mt < 2; ++mt)
            areg[kk][mt] = *(const short8*)(ApB
                + (wave * 32 + mt * 16 + l15) * (KP * 2) + quad * 16 + kk * 64);

    __syncthreads();

    float* so = (float*)(lds + 2 * TBUF);   // [4 slots][4 waves][64]
    int vbB[4];
#pragma unroll
    for (int nt = 0; nt < 4; ++nt)
        vbB[nt] = quad * TCH + (nt * 16 + l15) * 16;

    // ---- passes over hidden halves; each pass covers both tiles ----
#pragma unroll
    for (int ps = 0; ps < 2; ++ps) {
        int hb = ps * 128 + wave * 32;
        // bias + layer-2 weights hoisted once per pass (shared by both tiles)
        float4 bv0 = *(const float4*)&Cb1[hb + quad * 4];
        float4 bv1 = *(const float4*)&Cb1[hb + 16 + quad * 4];
        float4 wv0 = *(const float4*)&Cw2[hb + quad * 4];
        float4 wv1 = *(const float4*)&Cw2[hb + 16 + quad * 4];
#pragma unroll
        for (int t = 0; t < 2; ++t) {
            f32x4 acc[2][4];
            f32x4 bi0 = {bv0.x, bv0.y, bv0.z, bv0.w};
            f32x4 bi1 = {bv1.x, bv1.y, bv1.z, bv1.w};
#pragma unroll
            for (int nt = 0; nt < 4; ++nt) { acc[0][nt] = bi0; acc[1][nt] = bi1; }
#pragma unroll
            for (int kk = 0; kk < 5; ++kk) {
                short8 b[4];
                if (kk < 4) {
#pragma unroll
                    for (int nt = 0; nt < 4; ++nt)   // B: chunk-major LDS
                        b[nt] = *(const short8*)(lds + t * TBUF + kk * 4096 + vbB[nt]);
                } else {
                    short8 z = {0,0,0,0,0,0,0,0};
#pragma unroll
                    for (int nt = 0; nt < 4; ++nt) { // eattr chunks / K-pad
                        short8 v = *(const short8*)(lds + t * TBUF + 16 * TCH + vbB[nt]);
                        b[nt] = (quad < 2) ? v : z;
                    }
                }
#pragma unroll
                for (int mt = 0; mt < 2; ++mt)
#pragma unroll
                    for (int nt = 0; nt < 4; ++nt)
                        acc[mt][nt] = __builtin_amdgcn_mfma_f32_16x16x32_bf16(
                            areg[kk][mt], b[nt], acc[mt][nt], 0, 0, 0);
            }
            // after the LAST pass-0 MFMA use, prefetch pass-1 A-fragments;
            // latency hides under t1p0's epilogue
            if (ps == 0 && t == 1) {
#pragma unroll
                for (int kk = 0; kk < 5; ++kk)
#pragma unroll
                    for (int mt = 0; mt < 2; ++mt)
                        areg[kk][mt] = *(const short8*)(ApB
                            + (128 + wave * 32 + mt * 16 + l15) * (KP * 2)
                            + quad * 16 + kk * 64);
            }
            // layer 2: partial out[edge] = sum_hid elu(h) * cw2[hid]
            float p[4] = {0.f, 0.f, 0.f, 0.f};
            float w0[4] = {wv0.x, wv0.y, wv0.z, wv0.w};
            float w1[4] = {wv1.x, wv1.y, wv1.z, wv1.w};
#pragma unroll
            for (int nt = 0; nt < 4; ++nt)
#pragma unroll
                for (int r = 0; r < 4; ++r) {
                    float h0 = acc[0][nt][r];
                    float a0 = (h0 > 0.f) ? h0 : (__expf(h0) - 1.0f);
                    p[nt] = fmaf(a0, w0[r], p[nt]);
                    float h1 = acc[1][nt][r];
                    float a1 = (h1 > 0.f) ? h1 : (__expf(h1) - 1.0f);
                    p[nt] = fmaf(a1, w1[r], p[nt]);
                }
#pragma unroll
            for (int nt = 0; nt < 4; ++nt) {
                p[nt] += __shfl_xor(p[nt], 16);
                p[nt] += __shfl_xor(p[nt], 32);
            }
            if (quad == 0) {
#pragma unroll
                for (int nt = 0; nt < 4; ++nt)
                    so[(ps * 2 + t) * 256 + wave * 64 + nt * 16 + l15] = p[nt];
            }
        }
    }
    __syncthreads();
    if (tid < 128) {
        int t = tid >> 6, el = tid & 63;
        float s = Cb2[0];
#pragma unroll
        for (int w = 0; w < 4; ++w)
            s += so[t * 256 + w * 64 + el] + so[(t + 2) * 256 + w * 64 + el];
        out[ebase + t * 64 + el] = s;
    }
}

extern "C" void kernel_launch(void* const* d_in, const int* in_sizes, int n_in,
                              void* d_out, int out_size, void* d_ws, size_t ws_size,
                              hipStream_t stream) {
    const float* x     = (const float*)d_in[0];
    const float* eattr = (const float*)d_in[1];
    const float* W1l   = (const float*)d_in[2];
    const float* b1l   = (const float*)d_in[3];
    const float* W1r   = (const float*)d_in[4];
    const float* b1r   = (const float*)d_in[5];
    const float* We1   = (const float*)d_in[6];
    const float* att1  = (const float*)d_in[7];
    const float* bias1 = (const float*)d_in[8];
    const float* W2l   = (const float*)d_in[9];
    const float* b2l   = (const float*)d_in[10];
    const float* W2r   = (const float*)d_in[11];
    const float* b2r   = (const float*)d_in[12];
    const float* We2   = (const float*)d_in[13];
    const float* att2  = (const float*)d_in[14];
    const float* bias2 = (const float*)d_in[15];
    // d_in[16..19] (Aw1,Ab1,Aw2,Ab2) dead: softmax over size-1 axis == 1.0
    const float* Cw1   = (const float*)d_in[20];
    const float* Cb1   = (const float*)d_in[21];
    const float* Cw2   = (const float*)d_in[22];
    const float* Cb2   = (const float*)d_in[23];
    const int*   eidx  = (const int*)d_in[24];
    const int* src = eidx;
    const int* dst = eidx + NE;
    float* out = (float*)d_out;

    // workspace layout
    int*    deg      = (int*)d_ws;                     // NN
    int*    cursor   = deg + NN;                       // NN
    int*    rowptr   = cursor + NN;                    // NN+4
    int*    bsum     = rowptr + NN + 4;                // 256
    int*    boff     = bsum + 256;                     // 256
    int*    src_perm = boff + 256;                     // ESL
    ushort* eap      = (ushort*)(src_perm + ESL);      // ESL*16 bf16 (CSR-ordered eattr)
    ushort* xlb      = eap + (size_t)ESL * DE;         // 64NN bf16
    float*  xr       = (float*)(xlb + (size_t)NN * C); // 64NN
    float*  o1       = xr + (size_t)64 * NN;           // 64NN
    short*  h2b      = (short*)(o1 + (size_t)64 * NN); // 64NN bf16
    short*  cw1t     = h2b + (size_t)NN * C;           // 256*160 bf16
    float*  wT       = (float*)(cw1t + 256 * KP);      // 24576 fp32 (4 transposed W)
    float*  wlT1 = wT;                 // [64][128]
    float*  wrT1 = wT + 64 * DIN1;     // [64][128]
    float*  wlT2 = wT + 2 * 64 * DIN1;             // [64][64]
    float*  wrT2 = wT + 2 * 64 * DIN1 + 64 * C;    // [64][64]

    // zero deg + cursor (contiguous)
    hipMemsetAsync(deg, 0, (size_t)(2 * NN) * sizeof(int), stream);

    // CSR build (with one self-loop slot per node)
    k_deg<<<(NE + 255) / 256, 256, 0, stream>>>(dst, deg);
    k_scan1<<<NBLK, 256, 0, stream>>>(deg, rowptr, bsum);
    k_scan2<<<1, 256, 0, stream>>>(bsum, boff);
    k_scan3<<<NBLK, 256, 0, stream>>>(rowptr, boff);
    k_scatter<<<(NE + 255) / 256, 256, 0, stream>>>(src, dst, eattr, rowptr, cursor,
                                                    src_perm, eap);
    k_loop_csr<<<(NN + 3) / 4, 256, 0, stream>>>(rowptr, eap, src_perm);

    // weight conversions (independent of CSR)
    k_cvt_w<<<HID, KP, 0, stream>>>(Cw1, cw1t);
    k_trans<<<256, 128, 0, stream>>>(W1l, W1r, W2l, W2r, wT);

    // ---- GAT layer 1 ----
    k_lin<DIN1><<<NN / NPB, 128, 0, stream>>>(x, wlT1, b1l, wrT1, b1r, xlb, xr);
    k_gat<1, 0><<<NN / 4, 256, 0, stream>>>(src_perm, rowptr, eap, xlb, xr,
                                            We1, att1, bias1, o1);   // -> h (elu, fp32)

    // ---- GAT layer 2 (h2 written directly as bf16) ----
    k_lin<C><<<NN / NPB, 128, 0, stream>>>(o1, wlT2, b2l, wrT2, b2r, xlb, xr);
    k_gat<0, 1><<<NN / 4, 256, 0, stream>>>(src_perm, rowptr, eap, xlb, xr,
                                            We2, att2, bias2, h2b);  // -> h2 bf16

    // ---- MFMA edge classifier on original edges (2 tiles/block) ----
    k_cls_mfma<<<NE / 128, 256, 0, stream>>>(src, dst, eattr, h2b, cw1t, Cb1, Cw2, Cb2, out);
}

// Round 10
// 626.474 us; speedup vs baseline: 4.3067x; 4.3067x over previous
//
#include <hip/hip_runtime.h>
#include <math.h>

#define NN   50000
#define NE   800000
#define ESL  (NE + NN)     // CSR slots incl. one self-loop per node
#define DIN1 128
#define DE   16
#define C    64
#define HID  256
#define DCLS 144
#define KP   160      // DCLS padded to multiple of 32
#define NEGS 0.2f
#define NPB  8
#define NBLK ((NN + 255) / 256)   // 196 scan blocks

// ---- k_cls_mfma geometry (v7: 2 tiles/block, shared A) ----
#define TCH  1024                  // chunk stride: 64 rows * 16B
#define TBUF (18 * TCH)            // 18 chunks = 18432 B per tile
#define LDS_CLS (2 * TBUF + 4096)  // 2 tiles + so[4][4][64] = 40960 B (4 blk/CU exact)

typedef __attribute__((ext_vector_type(8))) short  short8;   // 8 bf16 in 4 VGPRs
typedef __attribute__((ext_vector_type(4))) float  f32x4;

// float -> bf16 (RNE)
__device__ __forceinline__ ushort f2bf(float f) {
    unsigned u = __float_as_uint(f);
    u += 0x7fffu + ((u >> 16) & 1u);
    return (ushort)(u >> 16);
}
__device__ __forceinline__ float bf2f(ushort u) {
    return __uint_as_float(((unsigned)u) << 16);
}
// packed bf16 pair -> two floats (1 op each)
__device__ __forceinline__ float bflo(unsigned w) { return __uint_as_float(w << 16); }
__device__ __forceinline__ float bfhi(unsigned w) { return __uint_as_float(w & 0xffff0000u); }

// ---- degree histogram ----
__global__ void k_deg(const int* __restrict__ dst, int* __restrict__ deg) {
    int e = blockIdx.x * blockDim.x + threadIdx.x;
    if (e < NE) atomicAdd(&deg[dst[e]], 1);
}

// ---- CSR build: scan of (deg+1) -> rowptr (self-loop slot per node) ----
__global__ void k_scan1(const int* __restrict__ deg, int* __restrict__ rowptr,
                        int* __restrict__ bsum) {
    __shared__ int s[256];
    int t = threadIdx.x;
    int i = blockIdx.x * 256 + t;
    int v = (i < NN) ? (deg[i] + 1) : 0;
    s[t] = v;
    __syncthreads();
    for (int off = 1; off < 256; off <<= 1) {
        int u = (t >= off) ? s[t - off] : 0;
        __syncthreads();
        s[t] += u;
        __syncthreads();
    }
    if (i < NN) rowptr[i] = s[t] - v;          // exclusive
    if (t == 255) bsum[blockIdx.x] = s[255];
}

__global__ void k_scan2(int* __restrict__ bsum, int* __restrict__ boff) {
    __shared__ int s[256];
    int t = threadIdx.x;
    int v = (t < NBLK) ? bsum[t] : 0;
    s[t] = v;
    __syncthreads();
    for (int off = 1; off < 256; off <<= 1) {
        int u = (t >= off) ? s[t - off] : 0;
        __syncthreads();
        s[t] += u;
        __syncthreads();
    }
    if (t < NBLK) boff[t] = s[t] - v;          // exclusive
}

__global__ void k_scan3(int* __restrict__ rowptr, const int* __restrict__ boff) {
    int i = blockIdx.x * 256 + threadIdx.x;
    if (i < NN) rowptr[i] += boff[blockIdx.x];
    if (i == 0) rowptr[NN] = ESL;
}

// ---- scatter: permute src + edge_attr(bf16) into CSR order ----
__global__ void k_scatter(const int* __restrict__ src, const int* __restrict__ dst,
                          const float* __restrict__ eattr,
                          const int* __restrict__ rowptr, int* __restrict__ cursor,
                          int* __restrict__ src_perm, ushort* __restrict__ eap) {
    int e = blockIdx.x * blockDim.x + threadIdx.x;
    if (e >= NE) return;
    int d = dst[e];
    int pos = atomicAdd(&cursor[d], 1);
    int idx = rowptr[d] + pos;
    src_perm[idx] = src[e];
    const float4* p4 = (const float4*)&eattr[(size_t)e * DE];
    float4 c0 = p4[0], c1 = p4[1], c2 = p4[2], c3 = p4[3];
    short8 r0, r1;
    r0[0]=f2bf(c0.x); r0[1]=f2bf(c0.y); r0[2]=f2bf(c0.z); r0[3]=f2bf(c0.w);
    r0[4]=f2bf(c1.x); r0[5]=f2bf(c1.y); r0[6]=f2bf(c1.z); r0[7]=f2bf(c1.w);
    r1[0]=f2bf(c2.x); r1[1]=f2bf(c2.y); r1[2]=f2bf(c2.z); r1[3]=f2bf(c2.w);
    r1[4]=f2bf(c3.x); r1[5]=f2bf(c3.y); r1[6]=f2bf(c3.z); r1[7]=f2bf(c3.w);
    short8* q = (short8*)&eap[(size_t)idx * DE];
    q[0] = r0; q[1] = r1;
}

// ---- self-loop mean attr -> written into the CSR self slot ----
__global__ void k_loop_csr(const int* __restrict__ rowptr,
                           ushort* __restrict__ eap, int* __restrict__ src_perm) {
    int wave = threadIdx.x >> 6, lane = threadIdx.x & 63;
    int d = blockIdx.x * 4 + wave;
    if (d >= NN) return;
    int j = lane & 15, g = lane >> 4;
    int kb = rowptr[d], ke1 = rowptr[d + 1] - 1;   // real edges in [kb, ke1)
    float sum = 0.f;
    for (int k = kb + g; k < ke1; k += 4)
        sum += bf2f(eap[(size_t)k * DE + j]);
    sum += __shfl_xor(sum, 16);
    sum += __shfl_xor(sum, 32);
    if (lane < 16)
        eap[(size_t)ke1 * DE + lane] = f2bf(sum / fmaxf((float)(ke1 - kb), 1.0f));
    if (lane == 16) src_perm[ke1] = d;
}

// ---- weight transposes for k_lin: WT[c][K] = W[k][c] ----
// out layout: wlT1[64*128] | wrT1[64*128] | wlT2[64*64] | wrT2[64*64]
__global__ void k_trans(const float* __restrict__ Wl1, const float* __restrict__ Wr1,
                        const float* __restrict__ Wl2, const float* __restrict__ Wr2,
                        float* __restrict__ out) {
    int b = blockIdx.x, c = b & 63, m = b >> 6;
    const float* W = (m == 0) ? Wl1 : (m == 1) ? Wr1 : (m == 2) ? Wl2 : Wr2;
    int K = (m < 2) ? DIN1 : C;
    float* WT = out + ((m < 2) ? m * (64 * DIN1) : 2 * (64 * DIN1) + (m - 2) * (64 * C));
    for (int k = threadIdx.x; k < K; k += 128)
        WT[c * K + k] = W[k * 64 + c];
}

// ---- node linear transforms v2: xl(bf16)=x@Wl+bl, xr(fp32)=x@Wr+br ----
template<int DINT>
__global__ __launch_bounds__(128, 4) void k_lin(
        const float* __restrict__ x,
        const float* __restrict__ WlT, const float* __restrict__ bl,
        const float* __restrict__ WrT, const float* __restrict__ br,
        ushort* __restrict__ xlb, float* __restrict__ xr) {
    __shared__ float sx[NPB * DINT];
    int i0 = blockIdx.x * NPB;
    int t = threadIdx.x;
    {
        const float4* g4 = (const float4*)(x + (size_t)i0 * DINT);
        float4* s4 = (float4*)sx;
#pragma unroll
        for (int f = t; f < NPB * DINT / 4; f += 128) s4[f] = g4[f];
    }
    __syncthreads();
    int c = t & 63, half = t >> 6;
    const float4* wt4 = (const float4*)((half ? WrT : WlT) + (size_t)c * DINT);
    float bb = (half ? br : bl)[c];
    float acc[NPB];
#pragma unroll
    for (int n = 0; n < NPB; ++n) acc[n] = bb;
    const float4* sx4 = (const float4*)sx;
#pragma unroll 4
    for (int k4 = 0; k4 < DINT / 4; ++k4) {
        float4 w = wt4[k4];
#pragma unroll
        for (int n = 0; n < NPB; ++n) {
            float4 xv = sx4[n * (DINT / 4) + k4];
            acc[n] = fmaf(xv.x, w.x, acc[n]);
            acc[n] = fmaf(xv.y, w.y, acc[n]);
            acc[n] = fmaf(xv.z, w.z, acc[n]);
            acc[n] = fmaf(xv.w, w.w, acc[n]);
        }
    }
    if (half == 0) {
#pragma unroll
        for (int n = 0; n < NPB; ++n)
            xlb[(size_t)(i0 + n) * C + c] = f2bf(acc[n]);
    } else {
#pragma unroll
        for (int n = 0; n < NPB; ++n)
            xr[(size_t)(i0 + n) * C + c] = acc[n];
    }
}

// ---- fused GAT layer v3: 4 nodes/block (wave=node), We in LDS, NO prefetch ----
// Round-9's software-pipeline spilled (conditionally-defined rotating regs
// under a tight bound -> 5.2 GB scratch traffic). v3 keeps only the two safe
// structural wins: (a) 4 waves/block removes the 16-wg/CU cap (16 -> 24-32
// waves/CU); (b) We/att/bias in LDS (4.6 KB; 16B-stride reads = 2-way bank
// alias = free) frees the 64-VGPR wreg array. Loop body is byte-identical
// to the proven round-8 version; launch_bounds(256,4) = cap 128, no spill.
template<int DO_ELU, int OUT_BF16>
__global__ __launch_bounds__(256, 4) void k_gat(
        const int* __restrict__ src_perm, const int* __restrict__ rowptr,
        const ushort* __restrict__ eap,
        const ushort* __restrict__ xlb, const float* __restrict__ xr,
        const float* __restrict__ We, const float* __restrict__ att,
        const float* __restrict__ bias, void* __restrict__ o_) {
    __shared__ float sWe[DE * C];     // [j][c], 4 KB
    __shared__ float sAx[2 * C];      // att | bias
    int tid = threadIdx.x;
    ((float4*)sWe)[tid] = ((const float4*)We)[tid];          // 256*16B = 4KB
    if (tid < 16)      ((float4*)sAx)[tid] = ((const float4*)att)[tid];
    else if (tid < 32) ((float4*)sAx)[tid] = ((const float4*)bias)[tid - 16];
    __syncthreads();

    int wave = tid >> 6, lane = tid & 63;
    int d = blockIdx.x * 4 + wave;    // NN % 4 == 0
    int g = lane >> 4, l = lane & 15;
    int c0 = l * 4;
    float4 xr4 = *(const float4*)&xr[(size_t)d * C + c0];
    float xrv[4] = {xr4.x, xr4.y, xr4.z, xr4.w};

    float l_run = 0.f, n_run[4] = {0.f, 0.f, 0.f, 0.f};
    int kb = rowptr[d], ke = rowptr[d + 1];
    for (int k = kb; k < ke; k += 4) {
        int kk = k + g;
        bool valid = kk < ke;
        int kidx = valid ? kk : (ke - 1);
        int s = src_perm[kidx];
        uint2 xlr = *(const uint2*)&xlb[(size_t)s * C + c0];
        float xlv[4] = {bflo(xlr.x), bfhi(xlr.x), bflo(xlr.y), bfhi(xlr.y)};
        const uint4* ep = (const uint4*)&eap[(size_t)kidx * DE];
        uint4 e0 = ep[0], e1 = ep[1];
        float m[4];
#pragma unroll
        for (int i = 0; i < 4; ++i) m[i] = xlv[i] + xrv[i];
        unsigned ew[8] = {e0.x, e0.y, e0.z, e0.w, e1.x, e1.y, e1.z, e1.w};
#pragma unroll
        for (int wji = 0; wji < 8; ++wji) {
            float elo = bflo(ew[wji]), ehi = bfhi(ew[wji]);
            float4 w0 = *(const float4*)&sWe[(2 * wji) * C + c0];
            float4 w1 = *(const float4*)&sWe[(2 * wji + 1) * C + c0];
            float w0v[4] = {w0.x, w0.y, w0.z, w0.w};
            float w1v[4] = {w1.x, w1.y, w1.z, w1.w};
#pragma unroll
            for (int i = 0; i < 4; ++i) {
                m[i] = fmaf(elo, w0v[i], m[i]);
                m[i] = fmaf(ehi, w1v[i], m[i]);
            }
        }
        float4 av = *(const float4*)&sAx[c0];
        float avv[4] = {av.x, av.y, av.z, av.w};
        float p = 0.f;
#pragma unroll
        for (int i = 0; i < 4; ++i) {
            float t = fmaxf(m[i], NEGS * m[i]);   // leaky via max
            p = fmaf(t, avv[i], p);
        }
        p += __shfl_xor(p, 1);
        p += __shfl_xor(p, 2);
        p += __shfl_xor(p, 4);
        p += __shfl_xor(p, 8);
        float pe = valid ? __expf(p) : 0.f;
        l_run += pe;
#pragma unroll
        for (int i = 0; i < 4; ++i) n_run[i] = fmaf(pe, xlv[i], n_run[i]);
    }
    l_run += __shfl_xor(l_run, 16);
    l_run += __shfl_xor(l_run, 32);
#pragma unroll
    for (int i = 0; i < 4; ++i) {
        n_run[i] += __shfl_xor(n_run[i], 16);
        n_run[i] += __shfl_xor(n_run[i], 32);
    }
    if (g == 0) {
        float4 bv = *(const float4*)&sAx[64 + c0];
        float bvv[4] = {bv.x, bv.y, bv.z, bv.w};
        float res[4];
#pragma unroll
        for (int i = 0; i < 4; ++i) {
            float v = n_run[i] / l_run + bvv[i];
            if (DO_ELU) v = (v > 0.f) ? v : (__expf(v) - 1.0f);
            res[i] = v;
        }
        if (OUT_BF16) {
            uint2 pk;
            pk.x = (unsigned)f2bf(res[0]) | ((unsigned)f2bf(res[1]) << 16);
            pk.y = (unsigned)f2bf(res[2]) | ((unsigned)f2bf(res[3]) << 16);
            *(uint2*)&((ushort*)o_)[(size_t)d * C + c0] = pk;
        } else {
            float4 pk = {res[0], res[1], res[2], res[3]};
            *(float4*)&((float*)o_)[(size_t)d * C + c0] = pk;
        }
    }
}

// Cw1 [144][256] fp32 -> Cw1T bf16 [256][160] (transpose + zero-pad K)
__global__ void k_cvt_w(const float* __restrict__ Cw1, short* __restrict__ Cw1T) {
    int n = blockIdx.x;
    int k = threadIdx.x;
    Cw1T[n * KP + k] = (k < DCLS) ? (short)f2bf(Cw1[k * HID + n]) : (short)0;
}

// ==== MFMA edge classifier v7: 2 tiles/block, shared A-fragments ====
// (unchanged from round 8 — control kernel, 98 µs measured)
__global__ __launch_bounds__(256, 4) void k_cls_mfma(
        const int* __restrict__ src, const int* __restrict__ dst,
        const float* __restrict__ eattr, const short* __restrict__ h2b,
        const short* __restrict__ Cw1T, const float* __restrict__ Cb1,
        const float* __restrict__ Cw2, const float* __restrict__ Cb2,
        float* __restrict__ out) {
    __shared__ __align__(16) char lds[LDS_CLS];
    int tid = threadIdx.x;
    int ebase = blockIdx.x * 128;
    int lane = tid & 63, wave = tid >> 6;
    int l15 = lane & 15, quad = lane >> 4;
    const char* ApB = (const char*)Cw1T;

    // ---- stage BOTH tiles: per thread 2x (64B row-half + eattr quarter) ----
    {
        int r = tid & 127, h = tid >> 7;        // row r (src<64|dst-64), half h
        int el = r & 63;
        int cb = ((r >> 6) << 3) + (h << 2);    // chunk base: src 0/dst 8, +h*4
        int eg = tid >> 2, q = tid & 3;
#pragma unroll
        for (int t = 0; t < 2; ++t) {
            int eb = ebase + t * 64;
            int node = (r < 64) ? src[eb + el] : dst[eb + el];
            const uint4* g = (const uint4*)(h2b + (size_t)node * C + h * 32);
            uint4 f0 = g[0], f1 = g[1], f2 = g[2], f3 = g[3];
            char* p = lds + t * TBUF + cb * TCH + el * 16;
            *(uint4*)(p) = f0;
            *(uint4*)(p + TCH) = f1;
            *(uint4*)(p + 2 * TCH) = f2;
            *(uint4*)(p + 3 * TCH) = f3;
            float4 ea = *(const float4*)&eattr[(size_t)(eb + eg) * DE + q * 4];
            uint2 pk;
            pk.x = (unsigned)f2bf(ea.x) | ((unsigned)f2bf(ea.y) << 16);
            pk.y = (unsigned)f2bf(ea.z) | ((unsigned)f2bf(ea.w) << 16);
            *(uint2*)(lds + t * TBUF + (16 + (q >> 1)) * TCH + eg * 16 + (q & 1) * 8) = pk;
        }
    }

    // ---- pass-0 A-fragment hoist (global; independent of LDS -> pre-barrier)
    short8 areg[5][2];
#pragma unroll
    for (int kk = 0; kk < 5; ++kk)
#pragma unroll
        for (int mt = 0; mt < 2; ++mt)
            areg[kk][mt] = *(const short8*)(ApB
                + (wave * 32 + mt * 16 + l15) * (KP * 2) + quad * 16 + kk * 64);

    __syncthreads();

    float* so = (float*)(lds + 2 * TBUF);   // [4 slots][4 waves][64]
    int vbB[4];
#pragma unroll
    for (int nt = 0; nt < 4; ++nt)
        vbB[nt] = quad * TCH + (nt * 16 + l15) * 16;

    // ---- passes over hidden halves; each pass covers both tiles ----
#pragma unroll
    for (int ps = 0; ps < 2; ++ps) {
        int hb = ps * 128 + wave * 32;
        // bias + layer-2 weights hoisted once per pass (shared by both tiles)
        float4 bv0 = *(const float4*)&Cb1[hb + quad * 4];
        float4 bv1 = *(const float4*)&Cb1[hb + 16 + quad * 4];
        float4 wv0 = *(const float4*)&Cw2[hb + quad * 4];
        float4 wv1 = *(const float4*)&Cw2[hb + 16 + quad * 4];
#pragma unroll
        for (int t = 0; t < 2; ++t) {
            f32x4 acc[2][4];
            f32x4 bi0 = {bv0.x, bv0.y, bv0.z, bv0.w};
            f32x4 bi1 = {bv1.x, bv1.y, bv1.z, bv1.w};
#pragma unroll
            for (int nt = 0; nt < 4; ++nt) { acc[0][nt] = bi0; acc[1][nt] = bi1; }
#pragma unroll
            for (int kk = 0; kk < 5; ++kk) {
                short8 b[4];
                if (kk < 4) {
#pragma unroll
                    for (int nt = 0; nt < 4; ++nt)   // B: chunk-major LDS
                        b[nt] = *(const short8*)(lds + t * TBUF + kk * 4096 + vbB[nt]);
                } else {
                    short8 z = {0,0,0,0,0,0,0,0};
#pragma unroll
                    for (int nt = 0; nt < 4; ++nt) { // eattr chunks / K-pad
                        short8 v = *(const short8*)(lds + t * TBUF + 16 * TCH + vbB[nt]);
                        b[nt] = (quad < 2) ? v : z;
                    }
                }
#pragma unroll
                for (int mt = 0; mt < 2; ++mt)
#pragma unroll
                    for (int nt = 0; nt < 4; ++nt)
                        acc[mt][nt] = __builtin_amdgcn_mfma_f32_16x16x32_bf16(
                            areg[kk][mt], b[nt], acc[mt][nt], 0, 0, 0);
            }
            // after the LAST pass-0 MFMA use, prefetch pass-1 A-fragments;
            // latency hides under t1p0's epilogue
            if (ps == 0 && t == 1) {
#pragma unroll
                for (int kk = 0; kk < 5; ++kk)
#pragma unroll
                    for (int mt = 0; mt < 2; ++mt)
                        areg[kk][mt] = *(const short8*)(ApB
                            + (128 + wave * 32 + mt * 16 + l15) * (KP * 2)
                            + quad * 16 + kk * 64);
            }
            // layer 2: partial out[edge] = sum_hid elu(h) * cw2[hid]
            float p[4] = {0.f, 0.f, 0.f, 0.f};
            float w0[4] = {wv0.x, wv0.y, wv0.z, wv0.w};
            float w1[4] = {wv1.x, wv1.y, wv1.z, wv1.w};
#pragma unroll
            for (int nt = 0; nt < 4; ++nt)
#pragma unroll
                for (int r = 0; r < 4; ++r) {
                    float h0 = acc[0][nt][r];
                    float a0 = (h0 > 0.f) ? h0 : (__expf(h0) - 1.0f);
                    p[nt] = fmaf(a0, w0[r], p[nt]);
                    float h1 = acc[1][nt][r];
                    float a1 = (h1 > 0.f) ? h1 : (__expf(h1) - 1.0f);
                    p[nt] = fmaf(a1, w1[r], p[nt]);
                }
#pragma unroll
            for (int nt = 0; nt < 4; ++nt) {
                p[nt] += __shfl_xor(p[nt], 16);
                p[nt] += __shfl_xor(p[nt], 32);
            }
            if (quad == 0) {
#pragma unroll
                for (int nt = 0; nt < 4; ++nt)
                    so[(ps * 2 + t) * 256 + wave * 64 + nt * 16 + l15] = p[nt];
            }
        }
    }
    __syncthreads();
    if (tid < 128) {
        int t = tid >> 6, el = tid & 63;
        float s = Cb2[0];
#pragma unroll
        for (int w = 0; w < 4; ++w)
            s += so[t * 256 + w * 64 + el] + so[(t + 2) * 256 + w * 64 + el];
        out[ebase + t * 64 + el] = s;
    }
}

extern "C" void kernel_launch(void* const* d_in, const int* in_sizes, int n_in,
                              void* d_out, int out_size, void* d_ws, size_t ws_size,
                              hipStream_t stream) {
    const float* x     = (const float*)d_in[0];
    const float* eattr = (const float*)d_in[1];
    const float* W1l   = (const float*)d_in[2];
    const float* b1l   = (const float*)d_in[3];
    const float* W1r   = (const float*)d_in[4];
    const float* b1r   = (const float*)d_in[5];
    const float* We1   = (const float*)d_in[6];
    const float* att1  = (const float*)d_in[7];
    const float* bias1 = (const float*)d_in[8];
    const float* W2l   = (const float*)d_in[9];
    const float* b2l   = (const float*)d_in[10];
    const float* W2r   = (const float*)d_in[11];
    const float* b2r   = (const float*)d_in[12];
    const float* We2   = (const float*)d_in[13];
    const float* att2  = (const float*)d_in[14];
    const float* bias2 = (const float*)d_in[15];
    // d_in[16..19] (Aw1,Ab1,Aw2,Ab2) dead: softmax over size-1 axis == 1.0
    const float* Cw1   = (const float*)d_in[20];
    const float* Cb1   = (const float*)d_in[21];
    const float* Cw2   = (const float*)d_in[22];
    const float* Cb2   = (const float*)d_in[23];
    const int*   eidx  = (const int*)d_in[24];
    const int* src = eidx;
    const int* dst = eidx + NE;
    float* out = (float*)d_out;

    // workspace layout
    int*    deg      = (int*)d_ws;                     // NN
    int*    cursor   = deg + NN;                       // NN
    int*    rowptr   = cursor + NN;                    // NN+4
    int*    bsum     = rowptr + NN + 4;                // 256
    int*    boff     = bsum + 256;                     // 256
    int*    src_perm = boff + 256;                     // ESL
    ushort* eap      = (ushort*)(src_perm + ESL);      // ESL*16 bf16 (CSR-ordered eattr)
    ushort* xlb      = eap + (size_t)ESL * DE;         // 64NN bf16
    float*  xr       = (float*)(xlb + (size_t)NN * C); // 64NN
    float*  o1       = xr + (size_t)64 * NN;           // 64NN
    short*  h2b      = (short*)(o1 + (size_t)64 * NN); // 64NN bf16
    short*  cw1t     = h2b + (size_t)NN * C;           // 256*160 bf16
    float*  wT       = (float*)(cw1t + 256 * KP);      // 24576 fp32 (4 transposed W)
    float*  wlT1 = wT;                 // [64][128]
    float*  wrT1 = wT + 64 * DIN1;     // [64][128]
    float*  wlT2 = wT + 2 * 64 * DIN1;             // [64][64]
    float*  wrT2 = wT + 2 * 64 * DIN1 + 64 * C;    // [64][64]

    // zero deg + cursor (contiguous)
    hipMemsetAsync(deg, 0, (size_t)(2 * NN) * sizeof(int), stream);

    // CSR build (with one self-loop slot per node)
    k_deg<<<(NE + 255) / 256, 256, 0, stream>>>(dst, deg);
    k_scan1<<<NBLK, 256, 0, stream>>>(deg, rowptr, bsum);
    k_scan2<<<1, 256, 0, stream>>>(bsum, boff);
    k_scan3<<<NBLK, 256, 0, stream>>>(rowptr, boff);
    k_scatter<<<(NE + 255) / 256, 256, 0, stream>>>(src, dst, eattr, rowptr, cursor,
                                                    src_perm, eap);
    k_loop_csr<<<(NN + 3) / 4, 256, 0, stream>>>(rowptr, eap, src_perm);

    // weight conversions (independent of CSR)
    k_cvt_w<<<HID, KP, 0, stream>>>(Cw1, cw1t);
    k_trans<<<256, 128, 0, stream>>>(W1l, W1r, W2l, W2r, wT);

    // ---- GAT layer 1 ----
    k_lin<DIN1><<<NN / NPB, 128, 0, stream>>>(x, wlT1, b1l, wrT1, b1r, xlb, xr);
    k_gat<1, 0><<<NN / 4, 256, 0, stream>>>(src_perm, rowptr, eap, xlb, xr,
                                            We1, att1, bias1, o1);   // -> h (elu, fp32)

    // ---- GAT layer 2 (h2 written directly as bf16) ----
    k_lin<C><<<NN / NPB, 128, 0, stream>>>(o1, wlT2, b2l, wrT2, b2r, xlb, xr);
    k_gat<0, 1><<<NN / 4, 256, 0, stream>>>(src_perm, rowptr, eap, xlb, xr,
                                            We2, att2, bias2, h2b);  // -> h2 bf16

    // ---- MFMA edge classifier on original edges (2 tiles/block) ----
    k_cls_mfma<<<NE / 128, 256, 0, stream>>>(src, dst, eattr, h2b, cw1t, Cb1, Cw2, Cb2, out);
}

// Round 11
// 593.964 us; speedup vs baseline: 4.5425x; 1.0547x over previous
//
#include <hip/hip_runtime.h>
#include <math.h>

#define NN   50000
#define NE   800000
#define ESL  (NE + NN)     // CSR slots incl. one self-loop per node
#define DIN1 128
#define DE   16
#define C    64
#define HID  256
#define DCLS 144
#define KP   160      // DCLS padded to multiple of 32
#define NEGS 0.2f
#define NPB  8
#define NBLK ((NN + 255) / 256)   // 196 scan blocks

// ---- k_cls_mfma geometry (v7: 2 tiles/block, shared A) ----
#define TCH  1024                  // chunk stride: 64 rows * 16B
#define TBUF (18 * TCH)            // 18 chunks = 18432 B per tile
#define LDS_CLS (2 * TBUF + 4096)  // 2 tiles + so[4][4][64] = 40960 B (4 blk/CU exact)

typedef __attribute__((ext_vector_type(8))) short  short8;   // 8 bf16 in 4 VGPRs
typedef __attribute__((ext_vector_type(4))) float  f32x4;

// float -> bf16 (RNE)
__device__ __forceinline__ ushort f2bf(float f) {
    unsigned u = __float_as_uint(f);
    u += 0x7fffu + ((u >> 16) & 1u);
    return (ushort)(u >> 16);
}
__device__ __forceinline__ float bf2f(ushort u) {
    return __uint_as_float(((unsigned)u) << 16);
}
// packed bf16 pair -> two floats (1 op each)
__device__ __forceinline__ float bflo(unsigned w) { return __uint_as_float(w << 16); }
__device__ __forceinline__ float bfhi(unsigned w) { return __uint_as_float(w & 0xffff0000u); }

// ---- degree histogram ----
__global__ void k_deg(const int* __restrict__ dst, int* __restrict__ deg) {
    int e = blockIdx.x * blockDim.x + threadIdx.x;
    if (e < NE) atomicAdd(&deg[dst[e]], 1);
}

// ---- CSR build: scan of (deg+1) -> rowptr (self-loop slot per node) ----
__global__ void k_scan1(const int* __restrict__ deg, int* __restrict__ rowptr,
                        int* __restrict__ bsum) {
    __shared__ int s[256];
    int t = threadIdx.x;
    int i = blockIdx.x * 256 + t;
    int v = (i < NN) ? (deg[i] + 1) : 0;
    s[t] = v;
    __syncthreads();
    for (int off = 1; off < 256; off <<= 1) {
        int u = (t >= off) ? s[t - off] : 0;
        __syncthreads();
        s[t] += u;
        __syncthreads();
    }
    if (i < NN) rowptr[i] = s[t] - v;          // exclusive
    if (t == 255) bsum[blockIdx.x] = s[255];
}

__global__ void k_scan2(int* __restrict__ bsum, int* __restrict__ boff) {
    __shared__ int s[256];
    int t = threadIdx.x;
    int v = (t < NBLK) ? bsum[t] : 0;
    s[t] = v;
    __syncthreads();
    for (int off = 1; off < 256; off <<= 1) {
        int u = (t >= off) ? s[t - off] : 0;
        __syncthreads();
        s[t] += u;
        __syncthreads();
    }
    if (t < NBLK) boff[t] = s[t] - v;          // exclusive
}

__global__ void k_scan3(int* __restrict__ rowptr, const int* __restrict__ boff) {
    int i = blockIdx.x * 256 + threadIdx.x;
    if (i < NN) rowptr[i] += boff[blockIdx.x];
    if (i == 0) rowptr[NN] = ESL;
}

// ---- scatter: permute src + edge_attr(bf16) into CSR order ----
__global__ void k_scatter(const int* __restrict__ src, const int* __restrict__ dst,
                          const float* __restrict__ eattr,
                          const int* __restrict__ rowptr, int* __restrict__ cursor,
                          int* __restrict__ src_perm, ushort* __restrict__ eap) {
    int e = blockIdx.x * blockDim.x + threadIdx.x;
    if (e >= NE) return;
    int d = dst[e];
    int pos = atomicAdd(&cursor[d], 1);
    int idx = rowptr[d] + pos;
    src_perm[idx] = src[e];
    const float4* p4 = (const float4*)&eattr[(size_t)e * DE];
    float4 c0 = p4[0], c1 = p4[1], c2 = p4[2], c3 = p4[3];
    short8 r0, r1;
    r0[0]=f2bf(c0.x); r0[1]=f2bf(c0.y); r0[2]=f2bf(c0.z); r0[3]=f2bf(c0.w);
    r0[4]=f2bf(c1.x); r0[5]=f2bf(c1.y); r0[6]=f2bf(c1.z); r0[7]=f2bf(c1.w);
    r1[0]=f2bf(c2.x); r1[1]=f2bf(c2.y); r1[2]=f2bf(c2.z); r1[3]=f2bf(c2.w);
    r1[4]=f2bf(c3.x); r1[5]=f2bf(c3.y); r1[6]=f2bf(c3.z); r1[7]=f2bf(c3.w);
    short8* q = (short8*)&eap[(size_t)idx * DE];
    q[0] = r0; q[1] = r1;
}

// ---- self-loop mean attr -> written into the CSR self slot ----
__global__ void k_loop_csr(const int* __restrict__ rowptr,
                           ushort* __restrict__ eap, int* __restrict__ src_perm) {
    int wave = threadIdx.x >> 6, lane = threadIdx.x & 63;
    int d = blockIdx.x * 4 + wave;
    if (d >= NN) return;
    int j = lane & 15, g = lane >> 4;
    int kb = rowptr[d], ke1 = rowptr[d + 1] - 1;   // real edges in [kb, ke1)
    float sum = 0.f;
    for (int k = kb + g; k < ke1; k += 4)
        sum += bf2f(eap[(size_t)k * DE + j]);
    sum += __shfl_xor(sum, 16);
    sum += __shfl_xor(sum, 32);
    if (lane < 16)
        eap[(size_t)ke1 * DE + lane] = f2bf(sum / fmaxf((float)(ke1 - kb), 1.0f));
    if (lane == 16) src_perm[ke1] = d;
}

// ---- weight transposes for k_lin: WT[c][K] = W[k][c] ----
// out layout: wlT1[64*128] | wrT1[64*128] | wlT2[64*64] | wrT2[64*64]
__global__ void k_trans(const float* __restrict__ Wl1, const float* __restrict__ Wr1,
                        const float* __restrict__ Wl2, const float* __restrict__ Wr2,
                        float* __restrict__ out) {
    int b = blockIdx.x, c = b & 63, m = b >> 6;
    const float* W = (m == 0) ? Wl1 : (m == 1) ? Wr1 : (m == 2) ? Wl2 : Wr2;
    int K = (m < 2) ? DIN1 : C;
    float* WT = out + ((m < 2) ? m * (64 * DIN1) : 2 * (64 * DIN1) + (m - 2) * (64 * C));
    for (int k = threadIdx.x; k < K; k += 128)
        WT[c * K + k] = W[k * 64 + c];
}

// ---- node linear transforms v2: xl(bf16)=x@Wl+bl, xr(fp32)=x@Wr+br ----
// 8 nodes/block, 128 thr. x tile staged in LDS (coalesced float4, reads are
// wave-uniform broadcasts); W streamed as float4 from the pre-transposed
// WT[c][K] (1 load / 4 k). Summation order identical to the naive loop.
template<int DINT>
__global__ __launch_bounds__(128, 4) void k_lin(
        const float* __restrict__ x,
        const float* __restrict__ WlT, const float* __restrict__ bl,
        const float* __restrict__ WrT, const float* __restrict__ br,
        ushort* __restrict__ xlb, float* __restrict__ xr) {
    __shared__ float sx[NPB * DINT];
    int i0 = blockIdx.x * NPB;
    int t = threadIdx.x;
    {
        const float4* g4 = (const float4*)(x + (size_t)i0 * DINT);
        float4* s4 = (float4*)sx;
#pragma unroll
        for (int f = t; f < NPB * DINT / 4; f += 128) s4[f] = g4[f];
    }
    __syncthreads();
    int c = t & 63, half = t >> 6;
    const float4* wt4 = (const float4*)((half ? WrT : WlT) + (size_t)c * DINT);
    float bb = (half ? br : bl)[c];
    float acc[NPB];
#pragma unroll
    for (int n = 0; n < NPB; ++n) acc[n] = bb;
    const float4* sx4 = (const float4*)sx;
#pragma unroll 4
    for (int k4 = 0; k4 < DINT / 4; ++k4) {
        float4 w = wt4[k4];
#pragma unroll
        for (int n = 0; n < NPB; ++n) {
            float4 xv = sx4[n * (DINT / 4) + k4];
            acc[n] = fmaf(xv.x, w.x, acc[n]);
            acc[n] = fmaf(xv.y, w.y, acc[n]);
            acc[n] = fmaf(xv.z, w.z, acc[n]);
            acc[n] = fmaf(xv.w, w.w, acc[n]);
        }
    }
    if (half == 0) {
#pragma unroll
        for (int n = 0; n < NPB; ++n)
            xlb[(size_t)(i0 + n) * C + c] = f2bf(acc[n]);
    } else {
#pragma unroll
        for (int n = 0; n < NPB; ++n)
            xr[(size_t)(i0 + n) * C + c] = acc[n];
    }
}

// ---- fused GAT layer, 4-edge x 16-lane layout (round-8 proven form) ----
// One wave per dst node, We slice in registers. LDS-We (round 10) put 16
// ds_read_b128 on the inner-loop critical path (+15 µs/dispatch); register
// prefetch (round 9) spilled. This form is the measured local optimum.
template<int DO_ELU, int OUT_BF16>
__global__ __launch_bounds__(64, 4) void k_gat(
        const int* __restrict__ src_perm, const int* __restrict__ rowptr,
        const ushort* __restrict__ eap,
        const ushort* __restrict__ xlb, const float* __restrict__ xr,
        const float* __restrict__ We, const float* __restrict__ att,
        const float* __restrict__ bias, void* __restrict__ o_) {
    int d = blockIdx.x;
    int lane = threadIdx.x;
    int g = lane >> 4, l = lane & 15;
    int c0 = l * 4;
    float wreg[DE][4];
#pragma unroll
    for (int j = 0; j < DE; ++j) {
        float4 wv = *(const float4*)&We[j * C + c0];
        wreg[j][0] = wv.x; wreg[j][1] = wv.y; wreg[j][2] = wv.z; wreg[j][3] = wv.w;
    }
    float4 av4 = *(const float4*)&att[c0];
    float attv[4] = {av4.x, av4.y, av4.z, av4.w};
    float4 xr4 = *(const float4*)&xr[(size_t)d * C + c0];
    float xrv[4] = {xr4.x, xr4.y, xr4.z, xr4.w};

    float l_run = 0.f, n_run[4] = {0.f, 0.f, 0.f, 0.f};
    int kb = rowptr[d], ke = rowptr[d + 1];
    for (int k = kb; k < ke; k += 4) {
        int kk = k + g;
        bool valid = kk < ke;
        int kidx = valid ? kk : (ke - 1);
        int s = src_perm[kidx];
        uint2 xlr = *(const uint2*)&xlb[(size_t)s * C + c0];
        float xlv[4] = {bflo(xlr.x), bfhi(xlr.x), bflo(xlr.y), bfhi(xlr.y)};
        const uint4* ep = (const uint4*)&eap[(size_t)kidx * DE];
        uint4 e0 = ep[0], e1 = ep[1];
        float m[4];
#pragma unroll
        for (int i = 0; i < 4; ++i) m[i] = xlv[i] + xrv[i];
        unsigned ew[8] = {e0.x, e0.y, e0.z, e0.w, e1.x, e1.y, e1.z, e1.w};
#pragma unroll
        for (int wji = 0; wji < 8; ++wji) {
            float elo = bflo(ew[wji]), ehi = bfhi(ew[wji]);
#pragma unroll
            for (int i = 0; i < 4; ++i) {
                m[i] = fmaf(elo, wreg[2 * wji][i], m[i]);
                m[i] = fmaf(ehi, wreg[2 * wji + 1][i], m[i]);
            }
        }
        float p = 0.f;
#pragma unroll
        for (int i = 0; i < 4; ++i) {
            float t = fmaxf(m[i], NEGS * m[i]);   // leaky via max
            p = fmaf(t, attv[i], p);
        }
        p += __shfl_xor(p, 1);
        p += __shfl_xor(p, 2);
        p += __shfl_xor(p, 4);
        p += __shfl_xor(p, 8);
        float pe = valid ? __expf(p) : 0.f;
        l_run += pe;
#pragma unroll
        for (int i = 0; i < 4; ++i) n_run[i] = fmaf(pe, xlv[i], n_run[i]);
    }
    l_run += __shfl_xor(l_run, 16);
    l_run += __shfl_xor(l_run, 32);
#pragma unroll
    for (int i = 0; i < 4; ++i) {
        n_run[i] += __shfl_xor(n_run[i], 16);
        n_run[i] += __shfl_xor(n_run[i], 32);
    }
    if (g == 0) {
        float4 bv = *(const float4*)&bias[c0];
        float bvv[4] = {bv.x, bv.y, bv.z, bv.w};
        float res[4];
#pragma unroll
        for (int i = 0; i < 4; ++i) {
            float v = n_run[i] / l_run + bvv[i];
            if (DO_ELU) v = (v > 0.f) ? v : (__expf(v) - 1.0f);
            res[i] = v;
        }
        if (OUT_BF16) {
            uint2 pk;
            pk.x = (unsigned)f2bf(res[0]) | ((unsigned)f2bf(res[1]) << 16);
            pk.y = (unsigned)f2bf(res[2]) | ((unsigned)f2bf(res[3]) << 16);
            *(uint2*)&((ushort*)o_)[(size_t)d * C + c0] = pk;
        } else {
            float4 pk = {res[0], res[1], res[2], res[3]};
            *(float4*)&((float*)o_)[(size_t)d * C + c0] = pk;
        }
    }
}

// Cw1 [144][256] fp32 -> Cw1T bf16 [256][160] (transpose + zero-pad K)
__global__ void k_cvt_w(const float* __restrict__ Cw1, short* __restrict__ Cw1T) {
    int n = blockIdx.x;
    int k = threadIdx.x;
    Cw1T[n * KP + k] = (k < DCLS) ? (short)f2bf(Cw1[k * HID + n]) : (short)0;
}

// ==== MFMA edge classifier v7: 2 tiles/block, shared A-fragments ====
// (round-8 proven form, 98 µs measured)
__global__ __launch_bounds__(256, 4) void k_cls_mfma(
        const int* __restrict__ src, const int* __restrict__ dst,
        const float* __restrict__ eattr, const short* __restrict__ h2b,
        const short* __restrict__ Cw1T, const float* __restrict__ Cb1,
        const float* __restrict__ Cw2, const float* __restrict__ Cb2,
        float* __restrict__ out) {
    __shared__ __align__(16) char lds[LDS_CLS];
    int tid = threadIdx.x;
    int ebase = blockIdx.x * 128;
    int lane = tid & 63, wave = tid >> 6;
    int l15 = lane & 15, quad = lane >> 4;
    const char* ApB = (const char*)Cw1T;

    // ---- stage BOTH tiles: per thread 2x (64B row-half + eattr quarter) ----
    {
        int r = tid & 127, h = tid >> 7;        // row r (src<64|dst-64), half h
        int el = r & 63;
        int cb = ((r >> 6) << 3) + (h << 2);    // chunk base: src 0/dst 8, +h*4
        int eg = tid >> 2, q = tid & 3;
#pragma unroll
        for (int t = 0; t < 2; ++t) {
            int eb = ebase + t * 64;
            int node = (r < 64) ? src[eb + el] : dst[eb + el];
            const uint4* g = (const uint4*)(h2b + (size_t)node * C + h * 32);
            uint4 f0 = g[0], f1 = g[1], f2 = g[2], f3 = g[3];
            char* p = lds + t * TBUF + cb * TCH + el * 16;
            *(uint4*)(p) = f0;
            *(uint4*)(p + TCH) = f1;
            *(uint4*)(p + 2 * TCH) = f2;
            *(uint4*)(p + 3 * TCH) = f3;
            float4 ea = *(const float4*)&eattr[(size_t)(eb + eg) * DE + q * 4];
            uint2 pk;
            pk.x = (unsigned)f2bf(ea.x) | ((unsigned)f2bf(ea.y) << 16);
            pk.y = (unsigned)f2bf(ea.z) | ((unsigned)f2bf(ea.w) << 16);
            *(uint2*)(lds + t * TBUF + (16 + (q >> 1)) * TCH + eg * 16 + (q & 1) * 8) = pk;
        }
    }

    // ---- pass-0 A-fragment hoist (global; independent of LDS -> pre-barrier)
    short8 areg[5][2];
#pragma unroll
    for (int kk = 0; kk < 5; ++kk)
#pragma unroll
        for (int mt = 0; mt < 2; ++mt)
            areg[kk][mt] = *(const short8*)(ApB
                + (wave * 32 + mt * 16 + l15) * (KP * 2) + quad * 16 + kk * 64);

    __syncthreads();

    float* so = (float*)(lds + 2 * TBUF);   // [4 slots][4 waves][64]
    int vbB[4];
#pragma unroll
    for (int nt = 0; nt < 4; ++nt)
        vbB[nt] = quad * TCH + (nt * 16 + l15) * 16;

    // ---- passes over hidden halves; each pass covers both tiles ----
#pragma unroll
    for (int ps = 0; ps < 2; ++ps) {
        int hb = ps * 128 + wave * 32;
        // bias + layer-2 weights hoisted once per pass (shared by both tiles)
        float4 bv0 = *(const float4*)&Cb1[hb + quad * 4];
        float4 bv1 = *(const float4*)&Cb1[hb + 16 + quad * 4];
        float4 wv0 = *(const float4*)&Cw2[hb + quad * 4];
        float4 wv1 = *(const float4*)&Cw2[hb + 16 + quad * 4];
#pragma unroll
        for (int t = 0; t < 2; ++t) {
            f32x4 acc[2][4];
            f32x4 bi0 = {bv0.x, bv0.y, bv0.z, bv0.w};
            f32x4 bi1 = {bv1.x, bv1.y, bv1.z, bv1.w};
#pragma unroll
            for (int nt = 0; nt < 4; ++nt) { acc[0][nt] = bi0; acc[1][nt] = bi1; }
#pragma unroll
            for (int kk = 0; kk < 5; ++kk) {
                short8 b[4];
                if (kk < 4) {
#pragma unroll
                    for (int nt = 0; nt < 4; ++nt)   // B: chunk-major LDS
                        b[nt] = *(const short8*)(lds + t * TBUF + kk * 4096 + vbB[nt]);
                } else {
                    short8 z = {0,0,0,0,0,0,0,0};
#pragma unroll
                    for (int nt = 0; nt < 4; ++nt) { // eattr chunks / K-pad
                        short8 v = *(const short8*)(lds + t * TBUF + 16 * TCH + vbB[nt]);
                        b[nt] = (quad < 2) ? v : z;
                    }
                }
#pragma unroll
                for (int mt = 0; mt < 2; ++mt)
#pragma unroll
                    for (int nt = 0; nt < 4; ++nt)
                        acc[mt][nt] = __builtin_amdgcn_mfma_f32_16x16x32_bf16(
                            areg[kk][mt], b[nt], acc[mt][nt], 0, 0, 0);
            }
            // after the LAST pass-0 MFMA use, prefetch pass-1 A-fragments;
            // latency hides under t1p0's epilogue
            if (ps == 0 && t == 1) {
#pragma unroll
                for (int kk = 0; kk < 5; ++kk)
#pragma unroll
                    for (int mt = 0; mt < 2; ++mt)
                        areg[kk][mt] = *(const short8*)(ApB
                            + (128 + wave * 32 + mt * 16 + l15) * (KP * 2)
                            + quad * 16 + kk * 64);
            }
            // layer 2: partial out[edge] = sum_hid elu(h) * cw2[hid]
            float p[4] = {0.f, 0.f, 0.f, 0.f};
            float w0[4] = {wv0.x, wv0.y, wv0.z, wv0.w};
            float w1[4] = {wv1.x, wv1.y, wv1.z, wv1.w};
#pragma unroll
            for (int nt = 0; nt < 4; ++nt)
#pragma unroll
                for (int r = 0; r < 4; ++r) {
                    float h0 = acc[0][nt][r];
                    float a0 = (h0 > 0.f) ? h0 : (__expf(h0) - 1.0f);
                    p[nt] = fmaf(a0, w0[r], p[nt]);
                    float h1 = acc[1][nt][r];
                    float a1 = (h1 > 0.f) ? h1 : (__expf(h1) - 1.0f);
                    p[nt] = fmaf(a1, w1[r], p[nt]);
                }
#pragma unroll
            for (int nt = 0; nt < 4; ++nt) {
                p[nt] += __shfl_xor(p[nt], 16);
                p[nt] += __shfl_xor(p[nt], 32);
            }
            if (quad == 0) {
#pragma unroll
                for (int nt = 0; nt < 4; ++nt)
                    so[(ps * 2 + t) * 256 + wave * 64 + nt * 16 + l15] = p[nt];
            }
        }
    }
    __syncthreads();
    if (tid < 128) {
        int t = tid >> 6, el = tid & 63;
        float s = Cb2[0];
#pragma unroll
        for (int w = 0; w < 4; ++w)
            s += so[t * 256 + w * 64 + el] + so[(t + 2) * 256 + w * 64 + el];
        out[ebase + t * 64 + el] = s;
    }
}

extern "C" void kernel_launch(void* const* d_in, const int* in_sizes, int n_in,
                              void* d_out, int out_size, void* d_ws, size_t ws_size,
                              hipStream_t stream) {
    const float* x     = (const float*)d_in[0];
    const float* eattr = (const float*)d_in[1];
    const float* W1l   = (const float*)d_in[2];
    const float* b1l   = (const float*)d_in[3];
    const float* W1r   = (const float*)d_in[4];
    const float* b1r   = (const float*)d_in[5];
    const float* We1   = (const float*)d_in[6];
    const float* att1  = (const float*)d_in[7];
    const float* bias1 = (const float*)d_in[8];
    const float* W2l   = (const float*)d_in[9];
    const float* b2l   = (const float*)d_in[10];
    const float* W2r   = (const float*)d_in[11];
    const float* b2r   = (const float*)d_in[12];
    const float* We2   = (const float*)d_in[13];
    const float* att2  = (const float*)d_in[14];
    const float* bias2 = (const float*)d_in[15];
    // d_in[16..19] (Aw1,Ab1,Aw2,Ab2) dead: softmax over size-1 axis == 1.0
    const float* Cw1   = (const float*)d_in[20];
    const float* Cb1   = (const float*)d_in[21];
    const float* Cw2   = (const float*)d_in[22];
    const float* Cb2   = (const float*)d_in[23];
    const int*   eidx  = (const int*)d_in[24];
    const int* src = eidx;
    const int* dst = eidx + NE;
    float* out = (float*)d_out;

    // workspace layout
    int*    deg      = (int*)d_ws;                     // NN
    int*    cursor   = deg + NN;                       // NN
    int*    rowptr   = cursor + NN;                    // NN+4
    int*    bsum     = rowptr + NN + 4;                // 256
    int*    boff     = bsum + 256;                     // 256
    int*    src_perm = boff + 256;                     // ESL
    ushort* eap      = (ushort*)(src_perm + ESL);      // ESL*16 bf16 (CSR-ordered eattr)
    ushort* xlb      = eap + (size_t)ESL * DE;         // 64NN bf16
    float*  xr       = (float*)(xlb + (size_t)NN * C); // 64NN
    float*  o1       = xr + (size_t)64 * NN;           // 64NN
    short*  h2b      = (short*)(o1 + (size_t)64 * NN); // 64NN bf16
    short*  cw1t     = h2b + (size_t)NN * C;           // 256*160 bf16
    float*  wT       = (float*)(cw1t + 256 * KP);      // 24576 fp32 (4 transposed W)
    float*  wlT1 = wT;                 // [64][128]
    float*  wrT1 = wT + 64 * DIN1;     // [64][128]
    float*  wlT2 = wT + 2 * 64 * DIN1;             // [64][64]
    float*  wrT2 = wT + 2 * 64 * DIN1 + 64 * C;    // [64][64]

    // zero deg + cursor (contiguous)
    hipMemsetAsync(deg, 0, (size_t)(2 * NN) * sizeof(int), stream);

    // CSR build (with one self-loop slot per node)
    k_deg<<<(NE + 255) / 256, 256, 0, stream>>>(dst, deg);
    k_scan1<<<NBLK, 256, 0, stream>>>(deg, rowptr, bsum);
    k_scan2<<<1, 256, 0, stream>>>(bsum, boff);
    k_scan3<<<NBLK, 256, 0, stream>>>(rowptr, boff);
    k_scatter<<<(NE + 255) / 256, 256, 0, stream>>>(src, dst, eattr, rowptr, cursor,
                                                    src_perm, eap);
    k_loop_csr<<<(NN + 3) / 4, 256, 0, stream>>>(rowptr, eap, src_perm);

    // weight conversions (independent of CSR)
    k_cvt_w<<<HID, KP, 0, stream>>>(Cw1, cw1t);
    k_trans<<<256, 128, 0, stream>>>(W1l, W1r, W2l, W2r, wT);

    // ---- GAT layer 1 ----
    k_lin<DIN1><<<NN / NPB, 128, 0, stream>>>(x, wlT1, b1l, wrT1, b1r, xlb, xr);
    k_gat<1, 0><<<NN, 64, 0, stream>>>(src_perm, rowptr, eap, xlb, xr,
                                       We1, att1, bias1, o1);   // -> h (elu, fp32)

    // ---- GAT layer 2 (h2 written directly as bf16) ----
    k_lin<C><<<NN / NPB, 128, 0, stream>>>(o1, wlT2, b2l, wrT2, b2r, xlb, xr);
    k_gat<0, 1><<<NN, 64, 0, stream>>>(src_perm, rowptr, eap, xlb, xr,
                                       We2, att2, bias2, h2b);  // -> h2 bf16

    // ---- MFMA edge classifier on original edges (2 tiles/block) ----
    k_cls_mfma<<<NE / 128, 256, 0, stream>>>(src, dst, eattr, h2b, cw1t, Cb1, Cw2, Cb2, out);
}